// Round 3
// baseline (553.732 us; speedup 1.0000x reference)
//
#include <hip/hip_runtime.h>
#include <hip/hip_bf16.h>

// Problem constants
#define Bb 2
#define Nn 4096
#define Cc 1024
#define Hh 16
#define Dd 64
#define Mm (Bb*Nn)      // 8192
#define W2 10
#define WINSZ 21        // 2*W2+1

typedef __attribute__((ext_vector_type(8))) short  bf16x8s;
typedef __attribute__((ext_vector_type(4))) float  f32x4;
typedef __attribute__((ext_vector_type(4))) unsigned short us4;

#define AS1 __attribute__((address_space(1)))
#define AS3 __attribute__((address_space(3)))

__device__ __forceinline__ unsigned short f2bf(float f) {
  unsigned int u = __float_as_uint(f);
  u += 0x7FFFu + ((u >> 16) & 1u);
  return (unsigned short)(u >> 16);
}
__device__ __forceinline__ float bf2f(unsigned short h) {
  return __uint_as_float(((unsigned int)h) << 16);
}
// bf16 pair in a dword -> two floats (1 VALU op each)
__device__ __forceinline__ float bflo(unsigned int u) { return __uint_as_float(u << 16); }
__device__ __forceinline__ float bfhi(unsigned int u) { return __uint_as_float(u & 0xFFFF0000u); }

// ---------------- fp32 -> bf16 convert (vectorized) ----------------
__global__ __launch_bounds__(256) void f2bf_kernel(const float4* __restrict__ src,
                                                   us4* __restrict__ dst, int n4) {
  int stride = gridDim.x * 256;
  for (int i = blockIdx.x * 256 + threadIdx.x; i < n4; i += stride) {
    float4 v = src[i];
    us4 o;
    o.x = f2bf(v.x); o.y = f2bf(v.y); o.z = f2bf(v.z); o.w = f2bf(v.w);
    dst[i] = o;
  }
}

// ---------------- bf16 NT GEMM: C[m,n] = sum_k A[m,k]*B[n,k] + bias[n] ----------------
template<bool OUT_BF16>
__global__ __launch_bounds__(256) void gemm_bt(const unsigned short* __restrict__ A,
                                               const unsigned short* __restrict__ Bm,
                                               const float* __restrict__ bias,
                                               void* __restrict__ Cout,
                                               int M, int N, int K) {
  constexpr int BM = 128, BN = 128, BK = 64;
  __shared__ unsigned short As[BM * BK];
  __shared__ unsigned short Bs[BN * BK];

  const int tid  = threadIdx.x;
  const int wave = tid >> 6, lane = tid & 63;
  const int wr = wave >> 1, wc = wave & 1;
  const int m0 = blockIdx.y * BM, n0 = blockIdx.x * BN;

  f32x4 acc[4][4] = {};

  const unsigned short* aSrc[4];
  const unsigned short* bSrc[4];
#pragma unroll
  for (int j = 0; j < 4; ++j) {
    int i = wave * 4 + j;
    int e = i * 512 + lane * 8;
    int row = e >> 6, col = e & 63;
    aSrc[j] = A  + (size_t)(m0 + row) * K + col;
    bSrc[j] = Bm + (size_t)(n0 + row) * K + col;
  }

  for (int k0 = 0; k0 < K; k0 += BK) {
    __syncthreads();
#pragma unroll
    for (int j = 0; j < 4; ++j) {
      int i = wave * 4 + j;
      __builtin_amdgcn_global_load_lds((AS1 const void*)(aSrc[j] + k0),
                                       (AS3 void*)(&As[i * 512]), 16, 0, 0);
      __builtin_amdgcn_global_load_lds((AS1 const void*)(bSrc[j] + k0),
                                       (AS3 void*)(&Bs[i * 512]), 16, 0, 0);
    }
    __syncthreads();

#pragma unroll
    for (int kk = 0; kk < BK; kk += 32) {
      bf16x8s a[4], b[4];
#pragma unroll
      for (int m = 0; m < 4; ++m)
        a[m] = *(const bf16x8s*)&As[(wr * 64 + m * 16 + (lane & 15)) * BK + kk + (lane >> 4) * 8];
#pragma unroll
      for (int n = 0; n < 4; ++n)
        b[n] = *(const bf16x8s*)&Bs[(wc * 64 + n * 16 + (lane & 15)) * BK + kk + (lane >> 4) * 8];
#pragma unroll
      for (int m = 0; m < 4; ++m)
#pragma unroll
        for (int n = 0; n < 4; ++n)
          acc[m][n] = __builtin_amdgcn_mfma_f32_16x16x32_bf16(a[m], b[n], acc[m][n], 0, 0, 0);
    }
  }

#pragma unroll
  for (int m = 0; m < 4; ++m) {
#pragma unroll
    for (int n = 0; n < 4; ++n) {
#pragma unroll
      for (int r = 0; r < 4; ++r) {
        int row = m0 + wr * 64 + m * 16 + (lane >> 4) * 4 + r;
        int col = n0 + wc * 64 + n * 16 + (lane & 15);
        float v = acc[m][n][r] + bias[col];
        if (OUT_BF16)
          ((unsigned short*)Cout)[(size_t)row * N + col] = f2bf(v);
        else
          ((float*)Cout)[(size_t)row * N + col] = v;
      }
    }
  }
}

// ---------------- banded local attention: 2 threads per (b,h,n) row ----------------
// Each thread owns a d-half (32 elems). 256 threads = 128 rows per block.
#define TN 128
#define KVROWS (TN + 2 * W2)   // 148 staged rows

__global__ __launch_bounds__(256, 4) void attn_kernel(const unsigned short* __restrict__ QKV, // [Mm][3072]
                                                      unsigned short* __restrict__ AO,        // [Mm][1024]
                                                      float* __restrict__ attn_last) {        // [Bb*Hh*11]
  // K/V window in LDS, 16B chunks, XOR-swizzled: slot = c ^ (r&7)
  __shared__ uint4 Kl[KVROWS * 8];   // 18944 B
  __shared__ uint4 Vl[KVROWS * 8];   // 18944 B

  const int nt = Nn / TN;            // 32
  const int bid = blockIdx.x;
  const int tile = bid & (nt - 1);
  const int bh = bid / nt;
  const int h = bh & (Hh - 1), b = bh / Hh;
  const int n0 = tile * TN;
  const int tid = threadIdx.x;

  // stage K,V rows [n0-10, n0+137], zero-fill OOB, swizzled chunk placement
  for (int idx = tid; idx < KVROWS * 8; idx += 256) {
    const int r = idx >> 3, c = idx & 7;
    const int pos = n0 - W2 + r;
    uint4 kv = make_uint4(0, 0, 0, 0), vv = make_uint4(0, 0, 0, 0);
    if (pos >= 0 && pos < Nn) {
      const uint4* row = (const uint4*)(QKV + (size_t)(b * Nn + pos) * 3072);
      kv = row[128 + h * 8 + c];   // K block at elem 1024
      vv = row[256 + h * 8 + c];   // V block at elem 2048
    }
    const int slot = c ^ (r & 7);
    Kl[r * 8 + slot] = kv;
    Vl[r * 8 + slot] = vv;
  }
  __syncthreads();

  const int row  = tid >> 1;       // 0..127
  const int half = tid & 1;        // which 32-elem d-half
  const int n = n0 + row;
  const size_t m = (size_t)b * Nn + n;

  // q half-row -> 32 f32 regs
  const uint4* qrow = (const uint4*)(QKV + m * 3072) + h * 8 + half * 4;
  float qf[32];
#pragma unroll
  for (int c = 0; c < 4; ++c) {
    uint4 v = qrow[c];
    const unsigned int dw[4] = {v.x, v.y, v.z, v.w};
#pragma unroll
    for (int j = 0; j < 4; ++j) {
      qf[c * 8 + j * 2 + 0] = bflo(dw[j]);
      qf[c * 8 + j * 2 + 1] = bfhi(dw[j]);
    }
  }

  // scores: 21 half-dots of length 32, partner-combined via shfl_xor(1)
  float p[WINSZ];
#pragma unroll
  for (int w = 0; w < WINSZ; ++w) {
    const int r = row + w;
    float a0 = 0.f, a1 = 0.f;
#pragma unroll
    for (int c = 0; c < 4; ++c) {
      uint4 v = Kl[r * 8 + ((half * 4 + c) ^ (r & 7))];
      const unsigned int dw[4] = {v.x, v.y, v.z, v.w};
#pragma unroll
      for (int j = 0; j < 4; ++j) {
        a0 += qf[c * 8 + j * 2 + 0] * bflo(dw[j]);
        a1 += qf[c * 8 + j * 2 + 1] * bfhi(dw[j]);
      }
    }
    float acc = a0 + a1;
    acc += __shfl_xor(acc, 1, 64);
    p[w] = acc * 0.125f;   // 1/sqrt(64)
  }

  // mask + softmax (f32) — both half-threads hold the full row
#pragma unroll
  for (int w = 0; w < WINSZ; ++w) {
    const int pos = n - W2 + w;
    if (pos < 0 || pos >= Nn) p[w] = -1e30f;
  }
  float mx = p[0];
#pragma unroll
  for (int w = 1; w < WINSZ; ++w) mx = fmaxf(mx, p[w]);
  float sum = 0.f;
#pragma unroll
  for (int w = 0; w < WINSZ; ++w) { p[w] = __expf(p[w] - mx); sum += p[w]; }
  const float inv = 1.0f / sum;

  // P·V over this thread's d-half
  float o[32] = {};
#pragma unroll
  for (int w = 0; w < WINSZ; ++w) {
    const int r = row + w;
    const float pw = p[w];
#pragma unroll
    for (int c = 0; c < 4; ++c) {
      uint4 v = Vl[r * 8 + ((half * 4 + c) ^ (r & 7))];
      const unsigned int dw[4] = {v.x, v.y, v.z, v.w};
#pragma unroll
      for (int j = 0; j < 4; ++j) {
        o[c * 8 + j * 2 + 0] += pw * bflo(dw[j]);
        o[c * 8 + j * 2 + 1] += pw * bfhi(dw[j]);
      }
    }
  }

  // packed bf16 writeout of this half
  uint4* orow = (uint4*)(AO + m * Cc + h * Dd) + half * 4;
#pragma unroll
  for (int c = 0; c < 4; ++c) {
    unsigned int dw[4];
#pragma unroll
    for (int j = 0; j < 4; ++j) {
      float e0 = o[c * 8 + j * 2 + 0] * inv;
      float e1 = o[c * 8 + j * 2 + 1] * inv;
      dw[j] = (unsigned int)f2bf(e0) | ((unsigned int)f2bf(e1) << 16);
    }
    orow[c] = make_uint4(dw[0], dw[1], dw[2], dw[3]);
  }

  if (n == Nn - 1 && half == 0) {
#pragma unroll
    for (int w = 0; w <= W2; ++w)
      attn_last[(b * Hh + h) * (W2 + 1) + w] = p[w] * inv;
  }
}

// ---------------- launch ----------------
extern "C" void kernel_launch(void* const* d_in, const int* in_sizes, int n_in,
                              void* d_out, int out_size, void* d_ws, size_t ws_size,
                              hipStream_t stream) {
  const float* q    = (const float*)d_in[0];
  const float* Wq_w = (const float*)d_in[1];
  const float* Wq_b = (const float*)d_in[2];
  const float* Wk_w = (const float*)d_in[3];
  const float* Wk_b = (const float*)d_in[4];
  const float* Wv_w = (const float*)d_in[5];
  const float* Wv_b = (const float*)d_in[6];
  const float* Wo_w = (const float*)d_in[7];
  const float* Wo_b = (const float*)d_in[8];
  float* out = (float*)d_out;                       // [Mm*Cc] + [Bb*Hh*11]
  float* attn_last = out + (size_t)Mm * Cc;

  // workspace carve (bytes)
  char* ws = (char*)d_ws;
  unsigned short* qb   = (unsigned short*)(ws);                       // Mm*Cc bf16   = 16 MB
  unsigned short* Wqkv = (unsigned short*)(ws + 16777216);            // 3072*1024    = 6 MB
  unsigned short* Wo16 = (unsigned short*)(ws + 16777216 + 6291456);  // 1024*1024    = 2 MB
  float*          bqkv = (float*)(ws + 25165824);                     // 3072 f32
  unsigned short* QKV  = (unsigned short*)(ws + 25182208);            // Mm*3072      = 48 MB
  unsigned short* AO   = (unsigned short*)(ws + 75513856);            // Mm*Cc        = 16 MB

  // 1) converts
  {
    int n4 = (Mm * Cc) / 4;
    f2bf_kernel<<<2048, 256, 0, stream>>>((const float4*)q, (us4*)qb, n4);
    int w4 = (Cc * Cc) / 4;
    f2bf_kernel<<<1024, 256, 0, stream>>>((const float4*)Wq_w, (us4*)(Wqkv), w4);
    f2bf_kernel<<<1024, 256, 0, stream>>>((const float4*)Wk_w, (us4*)(Wqkv + Cc * Cc), w4);
    f2bf_kernel<<<1024, 256, 0, stream>>>((const float4*)Wv_w, (us4*)(Wqkv + 2 * Cc * Cc), w4);
    f2bf_kernel<<<1024, 256, 0, stream>>>((const float4*)Wo_w, (us4*)Wo16, w4);
    hipMemcpyAsync(bqkv,          Wq_b, Cc * sizeof(float), hipMemcpyDeviceToDevice, stream);
    hipMemcpyAsync(bqkv + Cc,     Wk_b, Cc * sizeof(float), hipMemcpyDeviceToDevice, stream);
    hipMemcpyAsync(bqkv + 2 * Cc, Wv_b, Cc * sizeof(float), hipMemcpyDeviceToDevice, stream);
  }

  // 2) fused QKV projection: [8192,1024] x [3072,1024]^T -> bf16 [8192,3072]
  {
    dim3 grid(3072 / 128, Mm / 128);
    gemm_bt<true><<<grid, 256, 0, stream>>>(qb, Wqkv, bqkv, (void*)QKV, Mm, 3072, Cc);
  }

  // 3) windowed attention -> bf16 [8192,1024] + attn_last tail of d_out
  {
    dim3 grid(Bb * Hh * (Nn / TN));
    attn_kernel<<<grid, 256, 0, stream>>>(QKV, AO, attn_last);
  }

  // 4) output projection: [8192,1024] x [1024,1024]^T -> fp32 d_out
  {
    dim3 grid(Cc / 128, Mm / 128);
    gemm_bt<false><<<grid, 256, 0, stream>>>(AO, Wo16, Wo_b, (void*)out, Mm, Cc, Cc);
  }
}

// Round 4
// 512.432 us; speedup vs baseline: 1.0806x; 1.0806x over previous
//
#include <hip/hip_runtime.h>
#include <hip/hip_bf16.h>

// Problem constants
#define Bb 2
#define Nn 4096
#define Cc 1024
#define Hh 16
#define Dd 64
#define Mm (Bb*Nn)      // 8192
#define W2 10
#define WINSZ 21        // 2*W2+1

typedef __attribute__((ext_vector_type(8))) short  bf16x8s;
typedef __attribute__((ext_vector_type(4))) float  f32x4;
typedef __attribute__((ext_vector_type(4))) unsigned short us4;

#define AS1 __attribute__((address_space(1)))
#define AS3 __attribute__((address_space(3)))

__device__ __forceinline__ unsigned short f2bf(float f) {
  unsigned int u = __float_as_uint(f);
  u += 0x7FFFu + ((u >> 16) & 1u);
  return (unsigned short)(u >> 16);
}
__device__ __forceinline__ float bf2f(unsigned short h) {
  return __uint_as_float(((unsigned int)h) << 16);
}
// bf16 pair in a dword -> two floats (1 VALU op each)
__device__ __forceinline__ float bflo(unsigned int u) { return __uint_as_float(u << 16); }
__device__ __forceinline__ float bfhi(unsigned int u) { return __uint_as_float(u & 0xFFFF0000u); }

// ---------------- fp32 -> bf16 convert (vectorized) ----------------
__global__ __launch_bounds__(256) void f2bf_kernel(const float4* __restrict__ src,
                                                   us4* __restrict__ dst, int n4) {
  int stride = gridDim.x * 256;
  for (int i = blockIdx.x * 256 + threadIdx.x; i < n4; i += stride) {
    float4 v = src[i];
    us4 o;
    o.x = f2bf(v.x); o.y = f2bf(v.y); o.z = f2bf(v.z); o.w = f2bf(v.w);
    dst[i] = o;
  }
}

// ---------------- bf16 NT GEMM: C[m,n] = sum_k A[m,k]*B[n,k] + bias[n] ----------------
template<bool OUT_BF16>
__global__ __launch_bounds__(256) void gemm_bt(const unsigned short* __restrict__ A,
                                               const unsigned short* __restrict__ Bm,
                                               const float* __restrict__ bias,
                                               void* __restrict__ Cout,
                                               int M, int N, int K) {
  constexpr int BM = 128, BN = 128, BK = 64;
  __shared__ unsigned short As[BM * BK];
  __shared__ unsigned short Bs[BN * BK];

  const int tid  = threadIdx.x;
  const int wave = tid >> 6, lane = tid & 63;
  const int wr = wave >> 1, wc = wave & 1;
  const int m0 = blockIdx.y * BM, n0 = blockIdx.x * BN;

  f32x4 acc[4][4] = {};

  const unsigned short* aSrc[4];
  const unsigned short* bSrc[4];
#pragma unroll
  for (int j = 0; j < 4; ++j) {
    int i = wave * 4 + j;
    int e = i * 512 + lane * 8;
    int row = e >> 6, col = e & 63;
    aSrc[j] = A  + (size_t)(m0 + row) * K + col;
    bSrc[j] = Bm + (size_t)(n0 + row) * K + col;
  }

  for (int k0 = 0; k0 < K; k0 += BK) {
    __syncthreads();
#pragma unroll
    for (int j = 0; j < 4; ++j) {
      int i = wave * 4 + j;
      __builtin_amdgcn_global_load_lds((AS1 const void*)(aSrc[j] + k0),
                                       (AS3 void*)(&As[i * 512]), 16, 0, 0);
      __builtin_amdgcn_global_load_lds((AS1 const void*)(bSrc[j] + k0),
                                       (AS3 void*)(&Bs[i * 512]), 16, 0, 0);
    }
    __syncthreads();

#pragma unroll
    for (int kk = 0; kk < BK; kk += 32) {
      bf16x8s a[4], b[4];
#pragma unroll
      for (int m = 0; m < 4; ++m)
        a[m] = *(const bf16x8s*)&As[(wr * 64 + m * 16 + (lane & 15)) * BK + kk + (lane >> 4) * 8];
#pragma unroll
      for (int n = 0; n < 4; ++n)
        b[n] = *(const bf16x8s*)&Bs[(wc * 64 + n * 16 + (lane & 15)) * BK + kk + (lane >> 4) * 8];
#pragma unroll
      for (int m = 0; m < 4; ++m)
#pragma unroll
        for (int n = 0; n < 4; ++n)
          acc[m][n] = __builtin_amdgcn_mfma_f32_16x16x32_bf16(a[m], b[n], acc[m][n], 0, 0, 0);
    }
  }

#pragma unroll
  for (int m = 0; m < 4; ++m) {
#pragma unroll
    for (int n = 0; n < 4; ++n) {
#pragma unroll
      for (int r = 0; r < 4; ++r) {
        int row = m0 + wr * 64 + m * 16 + (lane >> 4) * 4 + r;
        int col = n0 + wc * 64 + n * 16 + (lane & 15);
        float v = acc[m][n][r] + bias[col];
        if (OUT_BF16)
          ((unsigned short*)Cout)[(size_t)row * N + col] = f2bf(v);
        else
          ((float*)Cout)[(size_t)row * N + col] = v;
      }
    }
  }
}

// ---------------- banded local attention: 2 threads per (b,h,n) row ----------------
// Each thread owns a d-half (32 elems). 256 threads = 128 rows per block.
#define TN 128
#define KVROWS (TN + 2 * W2)   // 148 staged rows

__global__ __launch_bounds__(256, 2) void attn_kernel(const unsigned short* __restrict__ QKV, // [Mm][3072]
                                                      unsigned short* __restrict__ AO,        // [Mm][1024]
                                                      float* __restrict__ attn_last) {        // [Bb*Hh*11]
  // K/V window in LDS, 16B chunks, XOR-swizzled: slot = c ^ (r&7)
  __shared__ uint4 Kl[KVROWS * 8];   // 18944 B
  __shared__ uint4 Vl[KVROWS * 8];   // 18944 B

  const int nt = Nn / TN;            // 32
  const int bid = blockIdx.x;
  const int tile = bid & (nt - 1);
  const int bh = bid / nt;
  const int h = bh & (Hh - 1), b = bh / Hh;
  const int n0 = tile * TN;
  const int tid = threadIdx.x;

  // stage K,V rows [n0-10, n0+137], zero-fill OOB, swizzled chunk placement
  for (int idx = tid; idx < KVROWS * 8; idx += 256) {
    const int r = idx >> 3, c = idx & 7;
    const int pos = n0 - W2 + r;
    uint4 kv = make_uint4(0, 0, 0, 0), vv = make_uint4(0, 0, 0, 0);
    if (pos >= 0 && pos < Nn) {
      const uint4* row = (const uint4*)(QKV + (size_t)(b * Nn + pos) * 3072);
      kv = row[128 + h * 8 + c];   // K block at elem 1024
      vv = row[256 + h * 8 + c];   // V block at elem 2048
    }
    const int slot = c ^ (r & 7);
    Kl[r * 8 + slot] = kv;
    Vl[r * 8 + slot] = vv;
  }
  __syncthreads();

  const int row  = tid >> 1;       // 0..127
  const int half = tid & 1;        // which 32-elem d-half
  const int n = n0 + row;
  const size_t m = (size_t)b * Nn + n;

  // q half-row -> 32 f32 regs
  const uint4* qrow = (const uint4*)(QKV + m * 3072) + h * 8 + half * 4;
  float qf[32];
#pragma unroll
  for (int c = 0; c < 4; ++c) {
    uint4 v = qrow[c];
    const unsigned int dw[4] = {v.x, v.y, v.z, v.w};
#pragma unroll
    for (int j = 0; j < 4; ++j) {
      qf[c * 8 + j * 2 + 0] = bflo(dw[j]);
      qf[c * 8 + j * 2 + 1] = bfhi(dw[j]);
    }
  }

  // scores: 21 half-dots of length 32, partner-combined via shfl_xor(1)
  float p[WINSZ];
#pragma unroll
  for (int w = 0; w < WINSZ; ++w) {
    const int r = row + w;
    float a0 = 0.f, a1 = 0.f;
#pragma unroll
    for (int c = 0; c < 4; ++c) {
      uint4 v = Kl[r * 8 + ((half * 4 + c) ^ (r & 7))];
      const unsigned int dw[4] = {v.x, v.y, v.z, v.w};
#pragma unroll
      for (int j = 0; j < 4; ++j) {
        a0 += qf[c * 8 + j * 2 + 0] * bflo(dw[j]);
        a1 += qf[c * 8 + j * 2 + 1] * bfhi(dw[j]);
      }
    }
    float acc = a0 + a1;
    acc += __shfl_xor(acc, 1, 64);
    p[w] = acc * 0.125f;   // 1/sqrt(64)
  }

  // mask + softmax (f32) — both half-threads hold the full row
#pragma unroll
  for (int w = 0; w < WINSZ; ++w) {
    const int pos = n - W2 + w;
    if (pos < 0 || pos >= Nn) p[w] = -1e30f;
  }
  float mx = p[0];
#pragma unroll
  for (int w = 1; w < WINSZ; ++w) mx = fmaxf(mx, p[w]);
  float sum = 0.f;
#pragma unroll
  for (int w = 0; w < WINSZ; ++w) { p[w] = __expf(p[w] - mx); sum += p[w]; }
  const float inv = 1.0f / sum;

  // P·V over this thread's d-half
  float o[32] = {};
#pragma unroll
  for (int w = 0; w < WINSZ; ++w) {
    const int r = row + w;
    const float pw = p[w];
#pragma unroll
    for (int c = 0; c < 4; ++c) {
      uint4 v = Vl[r * 8 + ((half * 4 + c) ^ (r & 7))];
      const unsigned int dw[4] = {v.x, v.y, v.z, v.w};
#pragma unroll
      for (int j = 0; j < 4; ++j) {
        o[c * 8 + j * 2 + 0] += pw * bflo(dw[j]);
        o[c * 8 + j * 2 + 1] += pw * bfhi(dw[j]);
      }
    }
  }

  // packed bf16 writeout of this half
  uint4* orow = (uint4*)(AO + m * Cc + h * Dd) + half * 4;
#pragma unroll
  for (int c = 0; c < 4; ++c) {
    unsigned int dw[4];
#pragma unroll
    for (int j = 0; j < 4; ++j) {
      float e0 = o[c * 8 + j * 2 + 0] * inv;
      float e1 = o[c * 8 + j * 2 + 1] * inv;
      dw[j] = (unsigned int)f2bf(e0) | ((unsigned int)f2bf(e1) << 16);
    }
    orow[c] = make_uint4(dw[0], dw[1], dw[2], dw[3]);
  }

  if (n == Nn - 1 && half == 0) {
#pragma unroll
    for (int w = 0; w <= W2; ++w)
      attn_last[(b * Hh + h) * (W2 + 1) + w] = p[w] * inv;
  }
}

// ---------------- launch ----------------
extern "C" void kernel_launch(void* const* d_in, const int* in_sizes, int n_in,
                              void* d_out, int out_size, void* d_ws, size_t ws_size,
                              hipStream_t stream) {
  const float* q    = (const float*)d_in[0];
  const float* Wq_w = (const float*)d_in[1];
  const float* Wq_b = (const float*)d_in[2];
  const float* Wk_w = (const float*)d_in[3];
  const float* Wk_b = (const float*)d_in[4];
  const float* Wv_w = (const float*)d_in[5];
  const float* Wv_b = (const float*)d_in[6];
  const float* Wo_w = (const float*)d_in[7];
  const float* Wo_b = (const float*)d_in[8];
  float* out = (float*)d_out;                       // [Mm*Cc] + [Bb*Hh*11]
  float* attn_last = out + (size_t)Mm * Cc;

  // workspace carve (bytes)
  char* ws = (char*)d_ws;
  unsigned short* qb   = (unsigned short*)(ws);                       // Mm*Cc bf16   = 16 MB
  unsigned short* Wqkv = (unsigned short*)(ws + 16777216);            // 3072*1024    = 6 MB
  unsigned short* Wo16 = (unsigned short*)(ws + 16777216 + 6291456);  // 1024*1024    = 2 MB
  float*          bqkv = (float*)(ws + 25165824);                     // 3072 f32
  unsigned short* QKV  = (unsigned short*)(ws + 25182208);            // Mm*3072      = 48 MB
  unsigned short* AO   = (unsigned short*)(ws + 75513856);            // Mm*Cc        = 16 MB

  // 1) converts
  {
    int n4 = (Mm * Cc) / 4;
    f2bf_kernel<<<2048, 256, 0, stream>>>((const float4*)q, (us4*)qb, n4);
    int w4 = (Cc * Cc) / 4;
    f2bf_kernel<<<1024, 256, 0, stream>>>((const float4*)Wq_w, (us4*)(Wqkv), w4);
    f2bf_kernel<<<1024, 256, 0, stream>>>((const float4*)Wk_w, (us4*)(Wqkv + Cc * Cc), w4);
    f2bf_kernel<<<1024, 256, 0, stream>>>((const float4*)Wv_w, (us4*)(Wqkv + 2 * Cc * Cc), w4);
    f2bf_kernel<<<1024, 256, 0, stream>>>((const float4*)Wo_w, (us4*)Wo16, w4);
    hipMemcpyAsync(bqkv,          Wq_b, Cc * sizeof(float), hipMemcpyDeviceToDevice, stream);
    hipMemcpyAsync(bqkv + Cc,     Wk_b, Cc * sizeof(float), hipMemcpyDeviceToDevice, stream);
    hipMemcpyAsync(bqkv + 2 * Cc, Wv_b, Cc * sizeof(float), hipMemcpyDeviceToDevice, stream);
  }

  // 2) fused QKV projection: [8192,1024] x [3072,1024]^T -> bf16 [8192,3072]
  {
    dim3 grid(3072 / 128, Mm / 128);
    gemm_bt<true><<<grid, 256, 0, stream>>>(qb, Wqkv, bqkv, (void*)QKV, Mm, 3072, Cc);
  }

  // 3) windowed attention -> bf16 [8192,1024] + attn_last tail of d_out
  {
    dim3 grid(Bb * Hh * (Nn / TN));
    attn_kernel<<<grid, 256, 0, stream>>>(QKV, AO, attn_last);
  }

  // 4) output projection: [8192,1024] x [1024,1024]^T -> fp32 d_out
  {
    dim3 grid(Cc / 128, Mm / 128);
    gemm_bt<false><<<grid, 256, 0, stream>>>(AO, Wo16, Wo_b, (void*)out, Mm, Cc, Cc);
  }
}

// Round 5
// 167.926 us; speedup vs baseline: 3.2975x; 3.0515x over previous
//
#include <hip/hip_runtime.h>
#include <hip/hip_bf16.h>

// Problem constants
#define Bb 2
#define Nn 4096
#define Cc 1024
#define Hh 16
#define Dd 64
#define Mm (Bb*Nn)      // 8192
#define W2 10
#define WINSZ 21        // 2*W2+1

typedef __attribute__((ext_vector_type(8))) short  bf16x8s;
typedef __attribute__((ext_vector_type(4))) float  f32x4;
typedef __attribute__((ext_vector_type(4))) unsigned short us4;

#define AS1 __attribute__((address_space(1)))
#define AS3 __attribute__((address_space(3)))

__device__ __forceinline__ unsigned short f2bf(float f) {
  unsigned int u = __float_as_uint(f);
  u += 0x7FFFu + ((u >> 16) & 1u);
  return (unsigned short)(u >> 16);
}
// bf16 pair in a dword -> two floats (1 VALU op each)
__device__ __forceinline__ float bflo(unsigned int u) { return __uint_as_float(u << 16); }
__device__ __forceinline__ float bfhi(unsigned int u) { return __uint_as_float(u & 0xFFFF0000u); }

// ---------------- fp32 -> bf16 convert (vectorized) ----------------
__global__ __launch_bounds__(256) void f2bf_kernel(const float4* __restrict__ src,
                                                   us4* __restrict__ dst, int n4) {
  int stride = gridDim.x * 256;
  for (int i = blockIdx.x * 256 + threadIdx.x; i < n4; i += stride) {
    float4 v = src[i];
    us4 o;
    o.x = f2bf(v.x); o.y = f2bf(v.y); o.z = f2bf(v.z); o.w = f2bf(v.w);
    dst[i] = o;
  }
}

// ---------------- bf16 NT GEMM: C[m,n] = sum_k A[m,k]*B[n,k] + bias[n] ----------------
template<bool OUT_BF16>
__global__ __launch_bounds__(256) void gemm_bt(const unsigned short* __restrict__ A,
                                               const unsigned short* __restrict__ Bm,
                                               const float* __restrict__ bias,
                                               void* __restrict__ Cout,
                                               int M, int N, int K) {
  constexpr int BM = 128, BN = 128, BK = 64;
  __shared__ unsigned short As[BM * BK];
  __shared__ unsigned short Bs[BN * BK];

  const int tid  = threadIdx.x;
  const int wave = tid >> 6, lane = tid & 63;
  const int wr = wave >> 1, wc = wave & 1;
  const int m0 = blockIdx.y * BM, n0 = blockIdx.x * BN;

  f32x4 acc[4][4] = {};

  const unsigned short* aSrc[4];
  const unsigned short* bSrc[4];
#pragma unroll
  for (int j = 0; j < 4; ++j) {
    int i = wave * 4 + j;
    int e = i * 512 + lane * 8;
    int row = e >> 6, col = e & 63;
    aSrc[j] = A  + (size_t)(m0 + row) * K + col;
    bSrc[j] = Bm + (size_t)(n0 + row) * K + col;
  }

  for (int k0 = 0; k0 < K; k0 += BK) {
    __syncthreads();
#pragma unroll
    for (int j = 0; j < 4; ++j) {
      int i = wave * 4 + j;
      __builtin_amdgcn_global_load_lds((AS1 const void*)(aSrc[j] + k0),
                                       (AS3 void*)(&As[i * 512]), 16, 0, 0);
      __builtin_amdgcn_global_load_lds((AS1 const void*)(bSrc[j] + k0),
                                       (AS3 void*)(&Bs[i * 512]), 16, 0, 0);
    }
    __syncthreads();

#pragma unroll
    for (int kk = 0; kk < BK; kk += 32) {
      bf16x8s a[4], b[4];
#pragma unroll
      for (int m = 0; m < 4; ++m)
        a[m] = *(const bf16x8s*)&As[(wr * 64 + m * 16 + (lane & 15)) * BK + kk + (lane >> 4) * 8];
#pragma unroll
      for (int n = 0; n < 4; ++n)
        b[n] = *(const bf16x8s*)&Bs[(wc * 64 + n * 16 + (lane & 15)) * BK + kk + (lane >> 4) * 8];
#pragma unroll
      for (int m = 0; m < 4; ++m)
#pragma unroll
        for (int n = 0; n < 4; ++n)
          acc[m][n] = __builtin_amdgcn_mfma_f32_16x16x32_bf16(a[m], b[n], acc[m][n], 0, 0, 0);
    }
  }

#pragma unroll
  for (int m = 0; m < 4; ++m) {
#pragma unroll
    for (int n = 0; n < 4; ++n) {
#pragma unroll
      for (int r = 0; r < 4; ++r) {
        int row = m0 + wr * 64 + m * 16 + (lane >> 4) * 4 + r;
        int col = n0 + wc * 64 + n * 16 + (lane & 15);
        float v = acc[m][n][r] + bias[col];
        if (OUT_BF16)
          ((unsigned short*)Cout)[(size_t)row * N + col] = f2bf(v);
        else
          ((float*)Cout)[(size_t)row * N + col] = v;
      }
    }
  }
}

// ---------------- banded local attention: 2 threads per (b,h,n) row ----------------
// Each thread owns a d-half (32 elems). 256 threads = 128 rows per block.
// Register-light: c-outer/w-inner, packed q, per-quarter PV accumulators.
#define TN 128
#define KVROWS (TN + 2 * W2)   // 148 staged rows

__global__ void attn_kernel(const unsigned short* __restrict__ QKV, // [Mm][3072]
                            unsigned short* __restrict__ AO,        // [Mm][1024]
                            float* __restrict__ attn_last) {        // [Bb*Hh*11]
  // K/V window in LDS, 16B chunks, XOR-swizzled: slot = c ^ (r&7)
  __shared__ uint4 Kl[KVROWS * 8];   // 18944 B
  __shared__ uint4 Vl[KVROWS * 8];   // 18944 B

  const int nt = Nn / TN;            // 32
  const int bid = blockIdx.x;
  const int tile = bid & (nt - 1);
  const int bh = bid / nt;
  const int h = bh & (Hh - 1), b = bh / Hh;
  const int n0 = tile * TN;
  const int tid = threadIdx.x;

  // stage K,V rows [n0-10, n0+137], zero-fill OOB, swizzled chunk placement
  for (int idx = tid; idx < KVROWS * 8; idx += 256) {
    const int r = idx >> 3, c = idx & 7;
    const int pos = n0 - W2 + r;
    uint4 kv = make_uint4(0, 0, 0, 0), vv = make_uint4(0, 0, 0, 0);
    if (pos >= 0 && pos < Nn) {
      const uint4* row = (const uint4*)(QKV + (size_t)(b * Nn + pos) * 3072);
      kv = row[128 + h * 8 + c];   // K block at elem 1024
      vv = row[256 + h * 8 + c];   // V block at elem 2048
    }
    const int slot = c ^ (r & 7);
    Kl[r * 8 + slot] = kv;
    Vl[r * 8 + slot] = vv;
  }
  __syncthreads();

  const int row  = tid >> 1;       // 0..127
  const int half = tid & 1;        // which 32-elem d-half
  const int n = n0 + row;
  const size_t m = (size_t)b * Nn + n;

  // q half-row, kept PACKED (4 uint4 = 16 regs)
  const uint4* qrow = (const uint4*)(QKV + m * 3072) + h * 8 + half * 4;
  const uint4 qd0 = qrow[0], qd1 = qrow[1], qd2 = qrow[2], qd3 = qrow[3];

  float p[WINSZ];
#pragma unroll
  for (int w = 0; w < WINSZ; ++w) p[w] = 0.f;

  // scores: c-outer, w-inner. Each c: extract 8 q floats once, then 21 chunk-dots.
#pragma unroll
  for (int c = 0; c < 4; ++c) {
    const uint4 qv = (c == 0) ? qd0 : (c == 1) ? qd1 : (c == 2) ? qd2 : qd3;
    const float q0 = bflo(qv.x), q1 = bfhi(qv.x);
    const float q2 = bflo(qv.y), q3 = bfhi(qv.y);
    const float q4 = bflo(qv.z), q5 = bfhi(qv.z);
    const float q6 = bflo(qv.w), q7 = bfhi(qv.w);
#pragma unroll 7
    for (int w = 0; w < WINSZ; ++w) {
      const int r = row + w;
      const uint4 v = Kl[r * 8 + ((half * 4 + c) ^ (r & 7))];
      float a0 = q0 * bflo(v.x);
      float a1 = q1 * bfhi(v.x);
      a0 += q2 * bflo(v.y);
      a1 += q3 * bfhi(v.y);
      a0 += q4 * bflo(v.z);
      a1 += q5 * bfhi(v.z);
      a0 += q6 * bflo(v.w);
      a1 += q7 * bfhi(v.w);
      p[w] += a0 + a1;
    }
  }

  // combine halves + scale + mask + softmax (both half-threads end with full row)
#pragma unroll
  for (int w = 0; w < WINSZ; ++w) {
    float t = p[w];
    t += __shfl_xor(t, 1, 64);
    const int pos = n - W2 + w;
    p[w] = (pos < 0 || pos >= Nn) ? -1e30f : t * 0.125f;  // 1/sqrt(64)
  }
  float mx = p[0];
#pragma unroll
  for (int w = 1; w < WINSZ; ++w) mx = fmaxf(mx, p[w]);
  float sum = 0.f;
#pragma unroll
  for (int w = 0; w < WINSZ; ++w) { p[w] = __expf(p[w] - mx); sum += p[w]; }
  const float inv = 1.0f / sum;

  if (n == Nn - 1 && half == 0) {
#pragma unroll
    for (int w = 0; w <= W2; ++w)
      attn_last[(b * Hh + h) * (W2 + 1) + w] = p[w] * inv;
  }

  // P·V: per d-quarter (8 elems), 8 accumulators, store immediately
  uint4* orow = (uint4*)(AO + m * Cc + h * Dd) + half * 4;
#pragma unroll
  for (int c = 0; c < 4; ++c) {
    float o0 = 0.f, o1 = 0.f, o2 = 0.f, o3 = 0.f;
    float o4 = 0.f, o5 = 0.f, o6 = 0.f, o7 = 0.f;
#pragma unroll 7
    for (int w = 0; w < WINSZ; ++w) {
      const int r = row + w;
      const uint4 v = Vl[r * 8 + ((half * 4 + c) ^ (r & 7))];
      const float pw = p[w];
      o0 += pw * bflo(v.x);
      o1 += pw * bfhi(v.x);
      o2 += pw * bflo(v.y);
      o3 += pw * bfhi(v.y);
      o4 += pw * bflo(v.z);
      o5 += pw * bfhi(v.z);
      o6 += pw * bflo(v.w);
      o7 += pw * bfhi(v.w);
    }
    unsigned int d0 = (unsigned int)f2bf(o0 * inv) | ((unsigned int)f2bf(o1 * inv) << 16);
    unsigned int d1 = (unsigned int)f2bf(o2 * inv) | ((unsigned int)f2bf(o3 * inv) << 16);
    unsigned int d2 = (unsigned int)f2bf(o4 * inv) | ((unsigned int)f2bf(o5 * inv) << 16);
    unsigned int d3 = (unsigned int)f2bf(o6 * inv) | ((unsigned int)f2bf(o7 * inv) << 16);
    orow[c] = make_uint4(d0, d1, d2, d3);
  }
}

// ---------------- launch ----------------
extern "C" void kernel_launch(void* const* d_in, const int* in_sizes, int n_in,
                              void* d_out, int out_size, void* d_ws, size_t ws_size,
                              hipStream_t stream) {
  const float* q    = (const float*)d_in[0];
  const float* Wq_w = (const float*)d_in[1];
  const float* Wq_b = (const float*)d_in[2];
  const float* Wk_w = (const float*)d_in[3];
  const float* Wk_b = (const float*)d_in[4];
  const float* Wv_w = (const float*)d_in[5];
  const float* Wv_b = (const float*)d_in[6];
  const float* Wo_w = (const float*)d_in[7];
  const float* Wo_b = (const float*)d_in[8];
  float* out = (float*)d_out;                       // [Mm*Cc] + [Bb*Hh*11]
  float* attn_last = out + (size_t)Mm * Cc;

  // workspace carve (bytes)
  char* ws = (char*)d_ws;
  unsigned short* qb   = (unsigned short*)(ws);                       // Mm*Cc bf16   = 16 MB
  unsigned short* Wqkv = (unsigned short*)(ws + 16777216);            // 3072*1024    = 6 MB
  unsigned short* Wo16 = (unsigned short*)(ws + 16777216 + 6291456);  // 1024*1024    = 2 MB
  float*          bqkv = (float*)(ws + 25165824);                     // 3072 f32
  unsigned short* QKV  = (unsigned short*)(ws + 25182208);            // Mm*3072      = 48 MB
  unsigned short* AO   = (unsigned short*)(ws + 75513856);            // Mm*Cc        = 16 MB

  // 1) converts
  {
    int n4 = (Mm * Cc) / 4;
    f2bf_kernel<<<2048, 256, 0, stream>>>((const float4*)q, (us4*)qb, n4);
    int w4 = (Cc * Cc) / 4;
    f2bf_kernel<<<1024, 256, 0, stream>>>((const float4*)Wq_w, (us4*)(Wqkv), w4);
    f2bf_kernel<<<1024, 256, 0, stream>>>((const float4*)Wk_w, (us4*)(Wqkv + Cc * Cc), w4);
    f2bf_kernel<<<1024, 256, 0, stream>>>((const float4*)Wv_w, (us4*)(Wqkv + 2 * Cc * Cc), w4);
    f2bf_kernel<<<1024, 256, 0, stream>>>((const float4*)Wo_w, (us4*)Wo16, w4);
    hipMemcpyAsync(bqkv,          Wq_b, Cc * sizeof(float), hipMemcpyDeviceToDevice, stream);
    hipMemcpyAsync(bqkv + Cc,     Wk_b, Cc * sizeof(float), hipMemcpyDeviceToDevice, stream);
    hipMemcpyAsync(bqkv + 2 * Cc, Wv_b, Cc * sizeof(float), hipMemcpyDeviceToDevice, stream);
  }

  // 2) fused QKV projection: [8192,1024] x [3072,1024]^T -> bf16 [8192,3072]
  {
    dim3 grid(3072 / 128, Mm / 128);
    gemm_bt<true><<<grid, 256, 0, stream>>>(qb, Wqkv, bqkv, (void*)QKV, Mm, 3072, Cc);
  }

  // 3) windowed attention -> bf16 [8192,1024] + attn_last tail of d_out
  {
    dim3 grid(Bb * Hh * (Nn / TN));
    attn_kernel<<<grid, 256, 0, stream>>>(QKV, AO, attn_last);
  }

  // 4) output projection: [8192,1024] x [1024,1024]^T -> fp32 d_out
  {
    dim3 grid(Cc / 128, Mm / 128);
    gemm_bt<false><<<grid, 256, 0, stream>>>(AO, Wo16, Wo_b, (void*)out, Mm, Cc, Cc);
  }
}